// Round 1
// baseline (28.267 us; speedup 1.0000x reference)
//
#include <hip/hip_runtime.h>
#include <math.h>

#define BB 4
#define NN 2048
#define DIN 64
#define HH 8
#define QKD 256
#define HID 512
#define DQK 32
#define DV 64

__global__ __launch_bounds__(256) void attn_q0_kernel(
    const float* __restrict__ x,  // (B, N, DIN)
    const float* __restrict__ Wq, // (DIN, QKD)
    const float* __restrict__ bq, // (QKD)
    const float* __restrict__ Wk, // (DIN, QKD)
    const float* __restrict__ bk, // (QKD)  [unused: constant shift cancels in softmax]
    const float* __restrict__ Wv, // (DIN, HID)
    const float* __restrict__ bv, // (HID)
    float* __restrict__ out)      // (B, 1, HID)
{
    const int bh = blockIdx.x;
    const int b  = bh / HH;
    const int h  = bh % HH;
    const int t  = threadIdx.x;
    const int wid  = t >> 6;
    const int lane = t & 63;

    __shared__ float q0[DQK];        // q row 0, this head
    __shared__ float rS[DIN];        // (Wk_h @ q0) / sqrt(DV)
    __shared__ float p[NN];          // exp(scores - max)
    __shared__ float red[8];         // cross-wave reduce slots
    __shared__ float ypart[4][DV];   // per-wave partial weighted sums
    __shared__ float yv[DIN];        // final weighted x-sum * invS

    const float* xb = x + (size_t)b * NN * DIN;

    // Phase 1: q0[j] = x[b,0,:] . Wq[:, h*32+j] + bq
    if (t < DQK) {
        float acc = bq[h * DQK + t];
        #pragma unroll
        for (int i = 0; i < DIN; ++i)
            acc += xb[i] * Wq[i * QKD + h * DQK + t];
        q0[t] = acc;
    }
    __syncthreads();

    // Phase 2: rS[d] = (sum_j Wk[d, h*32+j] * q0[j]) / 8   (score scale 1/sqrt(DV))
    if (t < DIN) {
        float acc = 0.f;
        #pragma unroll
        for (int j = 0; j < DQK; ++j)
            acc += Wk[t * QKD + h * DQK + j] * q0[j];
        rS[t] = acc * 0.125f;
    }
    __syncthreads();

    // Phase 3: scores for 8 rows per thread (rows n = k*256 + t), float4 loads
    float s[8];
    float lmax = -INFINITY;
    #pragma unroll
    for (int k = 0; k < 8; ++k) {
        const int n = k * 256 + t;
        const float4* xr = (const float4*)(xb + (size_t)n * DIN);
        float acc = 0.f;
        #pragma unroll
        for (int q = 0; q < 16; ++q) {
            float4 v = xr[q];
            acc += v.x * rS[q*4+0] + v.y * rS[q*4+1]
                 + v.z * rS[q*4+2] + v.w * rS[q*4+3];
        }
        s[k] = acc;
        lmax = fmaxf(lmax, acc);
    }

    // Block max reduce (64-lane wave shuffle, then 4 waves via LDS)
    #pragma unroll
    for (int o = 32; o; o >>= 1) lmax = fmaxf(lmax, __shfl_xor(lmax, o, 64));
    if (lane == 0) red[wid] = lmax;
    __syncthreads();
    const float m = fmaxf(fmaxf(red[0], red[1]), fmaxf(red[2], red[3]));

    // exp + sum reduce
    float lsum = 0.f;
    #pragma unroll
    for (int k = 0; k < 8; ++k) {
        float e = __expf(s[k] - m);
        p[k * 256 + t] = e;
        lsum += e;
    }
    #pragma unroll
    for (int o = 32; o; o >>= 1) lsum += __shfl_xor(lsum, o, 64);
    if (lane == 0) red[4 + wid] = lsum;
    __syncthreads();
    const float invS = 1.f / (red[4] + red[5] + red[6] + red[7]);

    // Phase 5: weighted column sums. Wave `wid` covers n in [wid*512, wid*512+512),
    // lane d accumulates sum_n p[n] * x[b,n,d]  (coalesced across lanes)
    {
        float acc = 0.f;
        const int n0 = wid * 512;
        for (int n = n0; n < n0 + 512; ++n)
            acc += p[n] * xb[(size_t)n * DIN + lane];
        ypart[wid][lane] = acc;
    }
    __syncthreads();
    if (t < DIN)
        yv[t] = (ypart[0][t] + ypart[1][t] + ypart[2][t] + ypart[3][t]) * invS;
    __syncthreads();

    // Phase 6: out[b, h*64+dv] = yv . Wv[:, h*64+dv] + bv
    if (t < DV) {
        float acc = bv[h * DV + t];
        #pragma unroll
        for (int i = 0; i < DIN; ++i)
            acc += yv[i] * Wv[i * HID + h * DV + t];
        out[b * HID + h * DV + t] = acc;
    }
}

extern "C" void kernel_launch(void* const* d_in, const int* in_sizes, int n_in,
                              void* d_out, int out_size, void* d_ws, size_t ws_size,
                              hipStream_t stream) {
    const float* x  = (const float*)d_in[0];
    const float* Wq = (const float*)d_in[1];
    const float* bq = (const float*)d_in[2];
    const float* Wk = (const float*)d_in[3];
    const float* bk = (const float*)d_in[4];
    const float* Wv = (const float*)d_in[5];
    const float* bv = (const float*)d_in[6];
    float* out = (float*)d_out;

    attn_q0_kernel<<<dim3(BB * HH), dim3(256), 0, stream>>>(
        x, Wq, bq, Wk, bk, Wv, bv, out);
}

// Round 2
// 19.752 us; speedup vs baseline: 1.4311x; 1.4311x over previous
//
#include <hip/hip_runtime.h>
#include <math.h>

#define BB 4
#define NN 2048
#define DIN 64
#define HH 8
#define QKD 256
#define HID 512
#define DQK 32
#define DV 64
#define CHUNKS 64
#define RPC (NN / CHUNKS)   // 32 rows per chunk

// ws layout (floats):
//   m_arr : [B*H][CHUNKS]          off 0        (2048)
//   s_arr : [B*H][CHUNKS]          off 2048     (2048)
//   y_arr : [B*H][CHUNKS][DIN]     off 4096     (131072)

__global__ __launch_bounds__(256) void partial_kernel(
    const float* __restrict__ x,   // (B,N,DIN)
    const float* __restrict__ Wq,  // (DIN,QKD)
    const float* __restrict__ bq,  // (QKD)
    const float* __restrict__ Wk,  // (DIN,QKD)
    float* __restrict__ m_arr, float* __restrict__ s_arr,
    float* __restrict__ y_arr)
{
    const int bc = blockIdx.x;
    const int b  = bc / CHUNKS;
    const int c  = bc % CHUNKS;
    const int t  = threadIdx.x;
    const float* xb = x + (size_t)b * NN * DIN;
    const float* xc = xb + (size_t)c * RPC * DIN;

    __shared__ float q0s[QKD];
    __shared__ float rSs[HH][DIN];
    __shared__ float pe[HH][RPC];

    // q0 for all 8 heads of batch b (identical in every chunk-block: deterministic)
    {
        float acc = bq[t];
        #pragma unroll
        for (int i = 0; i < DIN; ++i)
            acc += xb[i] * Wq[i * QKD + t];
        q0s[t] = acc;
    }
    __syncthreads();

    // rS[h][d] = (Wk[d, h*32:+32] . q0[h*32:+32]) / sqrt(DV)
    #pragma unroll
    for (int k = 0; k < 2; ++k) {
        const int idx = t + k * 256;
        const int h = idx >> 6, d = idx & 63;
        const float4* wk4 = (const float4*)(Wk + (size_t)d * QKD + h * DQK);
        const float4* q4  = (const float4*)(q0s + h * DQK);
        float acc = 0.f;
        #pragma unroll
        for (int j = 0; j < 8; ++j) {
            float4 w = wk4[j], q = q4[j];
            acc += w.x*q.x + w.y*q.y + w.z*q.z + w.w*q.w;
        }
        rSs[h][d] = acc * 0.125f;
    }
    __syncthreads();

    // scores: thread (h = t>>5, r = t&31) for row n = c*RPC + r
    const int h = t >> 5, r = t & 31;
    {
        const float4* xr = (const float4*)(xc + (size_t)r * DIN);
        const float4* rv = (const float4*)rSs[h];
        float s = 0.f;
        #pragma unroll
        for (int q = 0; q < 16; ++q) {
            float4 xv = xr[q], rw = rv[q];
            s += xv.x*rw.x + xv.y*rw.y + xv.z*rw.z + xv.w*rw.w;
        }
        // per-head (32-lane group) max and sum
        float m = s;
        #pragma unroll
        for (int o = 16; o; o >>= 1) m = fmaxf(m, __shfl_xor(m, o, 32));
        float e = __expf(s - m);
        float sum = e;
        #pragma unroll
        for (int o = 16; o; o >>= 1) sum += __shfl_xor(sum, o, 32);
        pe[h][r] = e;
        const int bh = b * HH + h;
        if (r == 0) {
            m_arr[bh * CHUNKS + c] = m;
            s_arr[bh * CHUNKS + c] = sum;
        }
    }
    __syncthreads();

    // weighted partial sums: thread (h2 = t>>5, d2 = t&31) covers cols d2, d2+32
    {
        const int h2 = t >> 5, d2 = t & 31;
        float a0 = 0.f, a1 = 0.f;
        #pragma unroll 4
        for (int rr = 0; rr < RPC; ++rr) {
            const float w = pe[h2][rr];
            a0 += w * xc[(size_t)rr * DIN + d2];
            a1 += w * xc[(size_t)rr * DIN + d2 + 32];
        }
        float* yrow = y_arr + ((size_t)(b * HH + h2) * CHUNKS + c) * DIN;
        yrow[d2]      = a0;
        yrow[d2 + 32] = a1;
    }
}

__global__ __launch_bounds__(64) void combine_kernel(
    const float* __restrict__ m_arr, const float* __restrict__ s_arr,
    const float* __restrict__ y_arr, const float* __restrict__ Wv,
    const float* __restrict__ bv, float* __restrict__ out)
{
    const int bh = blockIdx.x;
    const int b  = bh / HH;
    const int h  = bh % HH;
    const int d  = threadIdx.x;

    __shared__ float cvs[DIN];

    const float* mrow = m_arr + bh * CHUNKS;
    const float* srow = s_arr + bh * CHUNKS;

    float m = -INFINITY;
    #pragma unroll
    for (int c = 0; c < CHUNKS; ++c) m = fmaxf(m, mrow[c]);

    float S = 0.f, y = 0.f;
    #pragma unroll 4
    for (int c = 0; c < CHUNKS; ++c) {
        const float e = __expf(mrow[c] - m);
        S += srow[c] * e;
        y += y_arr[((size_t)bh * CHUNKS + c) * DIN + d] * e;
    }
    cvs[d] = y / S;
    __syncthreads();

    float acc = bv[h * DV + d];
    #pragma unroll
    for (int i = 0; i < DIN; ++i)
        acc += cvs[i] * Wv[(size_t)i * HID + h * DV + d];
    out[(size_t)b * HID + h * DV + d] = acc;
}

extern "C" void kernel_launch(void* const* d_in, const int* in_sizes, int n_in,
                              void* d_out, int out_size, void* d_ws, size_t ws_size,
                              hipStream_t stream) {
    const float* x  = (const float*)d_in[0];
    const float* Wq = (const float*)d_in[1];
    const float* bq = (const float*)d_in[2];
    const float* Wk = (const float*)d_in[3];
    // d_in[4] = bk: q0.bk is constant across keys -> cancels in softmax
    const float* Wv = (const float*)d_in[5];
    const float* bv = (const float*)d_in[6];
    float* out = (float*)d_out;

    float* m_arr = (float*)d_ws;
    float* s_arr = m_arr + BB * HH * CHUNKS;
    float* y_arr = s_arr + BB * HH * CHUNKS;

    partial_kernel<<<dim3(BB * CHUNKS), dim3(256), 0, stream>>>(
        x, Wq, bq, Wk, m_arr, s_arr, y_arr);
    combine_kernel<<<dim3(BB * HH), dim3(64), 0, stream>>>(
        m_arr, s_arr, y_arr, Wv, bv, out);
}